// Round 14
// baseline (743.683 us; speedup 1.0000x reference)
//
#include <hip/hip_runtime.h>

#define F_IN 128
#define F_OUT 64
#define LSTR 136
#define EB 4096          // edges per scatter chunk
#define BSH 8            // bucket = node >> 8  (256 nodes per bucket)
#define BNODES 256
#define BCAP 4608        // slots per bucket region; mean 4092, +8 sigma

typedef __bf16 bf16x8 __attribute__((ext_vector_type(8)));
typedef float f32x4 __attribute__((ext_vector_type(4)));

__device__ inline ushort f2bf(float f) {
    unsigned u = __float_as_uint(f);
    return (ushort)((u + 0x7fff + ((u >> 16) & 1)) >> 16);
}
__device__ inline float bf2f(ushort u) { return __uint_as_float((unsigned)u << 16); }

// ---- k1: blocks [0,nblk): scatter into FIXED-CAPACITY bucket regions.
//      Per chunk: LDS bucket count -> LDS counting sort (regs staged) ->
//      ONE global atomicAdd per (chunk,bucket) reserves run space ->
//      contiguous run writes. Intra-bucket order is race-arbitrary; gather
//      accumulates per-node in LDS so NO node-sort is needed anywhere.
//      blocks [nblk,...): bf16 MFMA GEMM (xwb = bf16(X@W)) rides along. ----
__global__ __launch_bounds__(512) void k_scatter_gemm(
        const float* __restrict__ X, const float* __restrict__ W,
        const int* __restrict__ ei, const float* __restrict__ ew,
        unsigned* __restrict__ bcnt, unsigned* __restrict__ sortedA,
        unsigned char* __restrict__ cl, ushort* __restrict__ xwb,
        int n, int e, int nblk, int nbuck) {
    __shared__ union SM {
        struct {
            unsigned srt[EB];     // 16 KB
            unsigned meta[EB];    // 16 KB (full 17-bit target id)
            unsigned s[512];
            unsigned cnt[512];
            unsigned ptr[512];
            unsigned delta[512];
        } sc;
        ushort Wt[64 * LSTR];     // 17 KB (GEMM branch)
    } sm;
    const int t = threadIdx.x;

    if ((int)blockIdx.x >= nblk) {
        // ---- GEMM: 128 rows x 64 cols, K=128, mfma_f32_16x16x32_bf16 ----
        ushort* Wt = sm.Wt;
        const int row0 = ((int)blockIdx.x - nblk) * 128;
        const float4* W4 = (const float4*)W;
        #pragma unroll
        for (int i = 0; i < 4; ++i) {
            int idx = t + i * 512;  // 2048 float4s = 128x64 W
            float4 v = W4[idx];
            int flat = idx * 4;
            int k = flat >> 6, c = flat & 63;
            Wt[(c + 0) * LSTR + k] = f2bf(v.x);
            Wt[(c + 1) * LSTR + k] = f2bf(v.y);
            Wt[(c + 2) * LSTR + k] = f2bf(v.z);
            Wt[(c + 3) * LSTR + k] = f2bf(v.w);
        }
        const int lane = t & 63, wv_ = t >> 6;       // 8 waves x 16 rows
        const int m16 = lane & 15, quad = lane >> 4;
        int arow = row0 + wv_ * 16 + m16;
        if (arow >= n) arow = n - 1;  // clamp; store is guarded
        const float* xr = X + (long)arow * F_IN;
        __syncthreads();

        f32x4 acc[4] = {{0,0,0,0},{0,0,0,0},{0,0,0,0},{0,0,0,0}};
        #pragma unroll
        for (int kk = 0; kk < 4; ++kk) {
            float4 xa = *(const float4*)(xr + kk * 32 + quad * 8);
            float4 xb = *(const float4*)(xr + kk * 32 + quad * 8 + 4);
            union { ushort us[8]; bf16x8 v; } ua;
            ua.us[0] = f2bf(xa.x); ua.us[1] = f2bf(xa.y);
            ua.us[2] = f2bf(xa.z); ua.us[3] = f2bf(xa.w);
            ua.us[4] = f2bf(xb.x); ua.us[5] = f2bf(xb.y);
            ua.us[6] = f2bf(xb.z); ua.us[7] = f2bf(xb.w);
            #pragma unroll
            for (int nt = 0; nt < 4; ++nt) {
                bf16x8 bb = *(const bf16x8*)&Wt[(nt * 16 + m16) * LSTR + kk * 32 + quad * 8];
                acc[nt] = __builtin_amdgcn_mfma_f32_16x16x32_bf16(ua.v, bb, acc[nt], 0, 0, 0);
            }
        }
        #pragma unroll
        for (int nt = 0; nt < 4; ++nt) {
            #pragma unroll
            for (int reg = 0; reg < 4; ++reg) {
                int gr = row0 + wv_ * 16 + quad * 4 + reg;  // C/D: row=quad*4+reg
                if (gr < n) xwb[(long)gr * F_OUT + nt * 16 + m16] = f2bf(acc[nt][reg]);
            }
        }
        return;
    }

    // ---- scatter branch ----
    const int blk = (int)blockIdx.x;
    sm.sc.cnt[t] = 0;
    __syncthreads();

    // pass 1: load chunk into regs (static-indexed), count buckets in LDS
    const int base = blk * EB;
    unsigned cc[EB / 512], rr[EB / 512], ww[EB / 512];
    #pragma unroll
    for (int jj = 0; jj < EB / 512; ++jj) {   // 8 iters
        int i = base + jj * 512 + t;
        unsigned c = 0xffffffffu, r = 0, w15 = 0;
        if (i < e) {
            c = (unsigned)ei[e + i];          // target
            r = (unsigned)ei[i];              // source
            unsigned u = __float_as_uint(ew[i]);
            w15 = ((u + 0x7fff + ((u >> 16) & 1)) >> 16) & 0x7fffu;
            atomicAdd(&sm.sc.cnt[c >> BSH], 1u);
        }
        cc[jj] = c; rr[jj] = r; ww[jj] = w15;
    }
    __syncthreads();

    // scan cnt -> exclusive LDS offsets; reserve global run space per bucket
    unsigned cv = sm.sc.cnt[t];
    sm.sc.s[t] = cv;
    __syncthreads();
    for (int off = 1; off < 512; off <<= 1) {
        unsigned u = (t >= off) ? sm.sc.s[t - off] : 0;
        __syncthreads();
        sm.sc.s[t] += u;
        __syncthreads();
    }
    const unsigned excl = sm.sc.s[t] - cv;
    sm.sc.ptr[t] = excl;
    unsigned rbase = (t < nbuck && cv > 0) ? atomicAdd(&bcnt[t], cv) : 0;
    sm.sc.delta[t] = (unsigned)t * BCAP + rbase - excl;
    __syncthreads();

    // pass 2: place records into LDS, bucket-sorted
    #pragma unroll
    for (int jj = 0; jj < EB / 512; ++jj) {
        if (cc[jj] != 0xffffffffu) {
            unsigned d = atomicAdd(&sm.sc.ptr[cc[jj] >> BSH], 1u);
            sm.sc.srt[d] = (rr[jj] << 15) | ww[jj];
            sm.sc.meta[d] = cc[jj];
        }
    }
    __syncthreads();

    // pass 3: contiguous run writes (consecutive lds idx -> consecutive dest)
    const int cnum = (e - base < EB) ? (e - base) : EB;
    #pragma unroll
    for (int jj = 0; jj < EB / 512; ++jj) {
        int i = jj * 512 + t;
        if (i < cnum) {
            unsigned c = sm.sc.meta[i];
            unsigned bb = c >> BSH;
            unsigned dest = sm.sc.delta[bb] + (unsigned)i;
            if (dest < (bb + 1) * BCAP) {   // overflow guard (P ~ 1e-15)
                sortedA[dest] = sm.sc.srt[i];
                cl[dest] = (unsigned char)(c & (BNODES - 1));
            }
        }
    }
}

// ---- k2: deg/dis only. 4 blocks per bucket, each filters its 64-node
//      quarter and LDS-accumulates incoming weight sums -> dis = rsqrt(deg+1).
//      dis must be globally complete before gather (remote sources). ----
__global__ __launch_bounds__(256, 8) void k_deg(
        const unsigned* __restrict__ sortedA, const unsigned char* __restrict__ cl,
        const unsigned* __restrict__ bcnt, float* __restrict__ dis, int n) {
    __shared__ float dl[64];
    const int b = (int)blockIdx.x >> 2, qtr = (int)blockIdx.x & 3;
    const int t = threadIdx.x;
    const unsigned S = (unsigned)b * BCAP;
    unsigned bc = bcnt[b];
    const int seg = (int)(bc < BCAP ? bc : BCAP);
    if (t < 64) dl[t] = 0.f;
    __syncthreads();
    for (int j = t; j < seg; j += 256) {
        unsigned c0 = cl[S + j];
        if ((int)(c0 >> 6) == qtr) {
            unsigned r = sortedA[S + j];
            atomicAdd(&dl[c0 & 63], __uint_as_float((r & 0x7fffu) << 16));
        }
    }
    __syncthreads();
    int c = b * BNODES + qtr * 64 + t;
    if (t < 64 && c < n) dis[c] = rsqrtf(dl[t] + 1.0f);
}

// ---- k3: accumulate-gather — NO node-sort anywhere. 4 blocks per bucket
//      (64 nodes each): acc[64][64] f32 in LDS (16 KB), init = dc*xw(self);
//      stream the bucket's unsorted records, quarter-wave per record slot,
//      quarter-uniform ownership predicate (cl>>6==qtr), lane fl does 4 LDS
//      atomicAdds of w*dis[r]*xw[r][4fl..]. No dependent chains: loads feed
//      only atomics, atomics feed only the final barrier -> deep overlap.
//      Epilogue: out = dc*acc + b, ReLU (contiguous float4 writes). ----
__global__ __launch_bounds__(256, 8) void k_gather(
        const unsigned* __restrict__ sortedA, const unsigned char* __restrict__ cl,
        const unsigned* __restrict__ bcnt, const float* __restrict__ dis,
        const ushort* __restrict__ xwb, const float* __restrict__ bias,
        float* __restrict__ out, int n) {
    __shared__ float acc[64 * 64];       // 16 KB
    const int b = (int)blockIdx.x >> 2, qtr = (int)blockIdx.x & 3;
    const int t = threadIdx.x;
    const unsigned S = (unsigned)b * BCAP;
    const int nbase = b * BNODES + qtr * 64;
    unsigned bc = bcnt[b];
    const int seg = (int)(bc < BCAP ? bc : BCAP);

    // init: self-loop term dc*xw (final *dc in epilogue => dc^2*xw)
    for (int i = t; i < 64 * 16; i += 256) {
        int nl = i >> 4, f4 = i & 15;
        int node = nbase + nl;
        float v0 = 0.f, v1 = 0.f, v2 = 0.f, v3 = 0.f;
        if (node < n) {
            float dc = dis[node];
            ushort4 xv = *(const ushort4*)(xwb + (long)node * 64 + f4 * 4);
            v0 = dc * bf2f(xv.x); v1 = dc * bf2f(xv.y);
            v2 = dc * bf2f(xv.z); v3 = dc * bf2f(xv.w);
        }
        int a = nl * 64 + f4 * 4;
        acc[a + 0] = v0; acc[a + 1] = v1; acc[a + 2] = v2; acc[a + 3] = v3;
    }
    __syncthreads();

    // stream records: 16 quarter-waves, 4 slots in flight each
    const int qw = t >> 4, fl = t & 15;
    for (int j0 = qw; j0 < seg; j0 += 64) {
        int j1 = (j0 + 16 < seg) ? j0 + 16 : j0;
        int j2 = (j0 + 32 < seg) ? j0 + 32 : j0;
        int j3 = (j0 + 48 < seg) ? j0 + 48 : j0;
        unsigned c0 = cl[S + j0], c1 = cl[S + j1];
        unsigned c2 = cl[S + j2], c3 = cl[S + j3];
        unsigned v0 = sortedA[S + j0], v1 = sortedA[S + j1];
        unsigned v2 = sortedA[S + j2], v3 = sortedA[S + j3];
        bool o0 = ((int)(c0 >> 6) == qtr);
        bool o1 = (j0 + 16 < seg) && ((int)(c1 >> 6) == qtr);
        bool o2 = (j0 + 32 < seg) && ((int)(c2 >> 6) == qtr);
        bool o3 = (j0 + 48 < seg) && ((int)(c3 >> 6) == qtr);
        if (o0) {
            int r = (int)(v0 >> 15);
            float w = __uint_as_float((v0 & 0x7fffu) << 16) * dis[r];
            ushort4 x = *(const ushort4*)(xwb + (long)r * 64 + fl * 4);
            int a = (int)(c0 & 63) * 64 + fl * 4;
            atomicAdd(&acc[a + 0], w * bf2f(x.x));
            atomicAdd(&acc[a + 1], w * bf2f(x.y));
            atomicAdd(&acc[a + 2], w * bf2f(x.z));
            atomicAdd(&acc[a + 3], w * bf2f(x.w));
        }
        if (o1) {
            int r = (int)(v1 >> 15);
            float w = __uint_as_float((v1 & 0x7fffu) << 16) * dis[r];
            ushort4 x = *(const ushort4*)(xwb + (long)r * 64 + fl * 4);
            int a = (int)(c1 & 63) * 64 + fl * 4;
            atomicAdd(&acc[a + 0], w * bf2f(x.x));
            atomicAdd(&acc[a + 1], w * bf2f(x.y));
            atomicAdd(&acc[a + 2], w * bf2f(x.z));
            atomicAdd(&acc[a + 3], w * bf2f(x.w));
        }
        if (o2) {
            int r = (int)(v2 >> 15);
            float w = __uint_as_float((v2 & 0x7fffu) << 16) * dis[r];
            ushort4 x = *(const ushort4*)(xwb + (long)r * 64 + fl * 4);
            int a = (int)(c2 & 63) * 64 + fl * 4;
            atomicAdd(&acc[a + 0], w * bf2f(x.x));
            atomicAdd(&acc[a + 1], w * bf2f(x.y));
            atomicAdd(&acc[a + 2], w * bf2f(x.z));
            atomicAdd(&acc[a + 3], w * bf2f(x.w));
        }
        if (o3) {
            int r = (int)(v3 >> 15);
            float w = __uint_as_float((v3 & 0x7fffu) << 16) * dis[r];
            ushort4 x = *(const ushort4*)(xwb + (long)r * 64 + fl * 4);
            int a = (int)(c3 & 63) * 64 + fl * 4;
            atomicAdd(&acc[a + 0], w * bf2f(x.x));
            atomicAdd(&acc[a + 1], w * bf2f(x.y));
            atomicAdd(&acc[a + 2], w * bf2f(x.z));
            atomicAdd(&acc[a + 3], w * bf2f(x.w));
        }
    }
    __syncthreads();

    // epilogue: out = dc*acc + bias, ReLU (contiguous float4 stores)
    for (int i = t; i < 64 * 16; i += 256) {
        int nl = i >> 4, f4 = i & 15;
        int node = nbase + nl;
        if (node < n) {
            float dc = dis[node];
            float4 bb = ((const float4*)bias)[f4];
            int a = nl * 64 + f4 * 4;
            float f0 = dc * acc[a + 0] + bb.x, f1 = dc * acc[a + 1] + bb.y;
            float f2 = dc * acc[a + 2] + bb.z, f3 = dc * acc[a + 3] + bb.w;
            ((float4*)out)[(long)node * 16 + f4] =
                make_float4(f0 > 0.f ? f0 : 0.f, f1 > 0.f ? f1 : 0.f,
                            f2 > 0.f ? f2 : 0.f, f3 > 0.f ? f3 : 0.f);
        }
    }
}

extern "C" void kernel_launch(void* const* d_in, const int* in_sizes, int n_in,
                              void* d_out, int out_size, void* d_ws, size_t ws_size,
                              hipStream_t stream) {
    const float* X  = (const float*)d_in[0];
    const int*   ei = (const int*)d_in[1];
    const float* ew = (const float*)d_in[2];
    const float* W  = (const float*)d_in[3];
    const float* b  = (const float*)d_in[4];
    float* out = (float*)d_out;

    const int n = in_sizes[0] / F_IN;   // 100000
    const int e = in_sizes[2];          // 1600000

    const int NBLK  = (e + EB - 1) / EB;            // 391  (<=512 for e<=2.09M)
    const int NBUCK = (n + BNODES - 1) / BNODES;    // 391  (<=512 for n<=131072)
    const int nb_gemm = (n + 127) / 128;            // 782 (128 rows per block)

    long p = 0;
    auto alloc = [&](long bytes) { long off = p; p += (bytes + 255) & ~255L; return off; };
    char* ws = (char*)d_ws;
    long o_bcnt   = alloc((long)NBUCK * 4);         // 1.6 KB (zeroed by memset)
    long o_sorted = alloc((long)NBUCK * BCAP * 4);  // 7.2 MB fixed-cap regions
    long o_cl     = alloc((long)NBUCK * BCAP);      // 1.8 MB
    long o_dis    = alloc((long)n * 4);             // 400 KB
    long o_xwb    = alloc((long)n * F_OUT * 2);     // 12.8 MB  -> total ~22.2 MB
    unsigned*      bcnt    = (unsigned*)(ws + o_bcnt);
    unsigned*      sortedA = (unsigned*)(ws + o_sorted);
    unsigned char* cl      = (unsigned char*)(ws + o_cl);
    float*         dis     = (float*)(ws + o_dis);
    ushort*        xwb     = (ushort*)(ws + o_xwb);

    hipMemsetAsync(ws + o_bcnt, 0, (size_t)NBUCK * 4, stream);  // bcnt only
    k_scatter_gemm<<<NBLK + nb_gemm, 512, 0, stream>>>(X, W, ei, ew, bcnt,
                                                       sortedA, cl, xwb,
                                                       n, e, NBLK, NBUCK);
    k_deg<<<NBUCK * 4, 256, 0, stream>>>(sortedA, cl, bcnt, dis, n);
    k_gather<<<NBUCK * 4, 256, 0, stream>>>(sortedA, cl, bcnt, dis, xwb,
                                            b, out, n);
}

// Round 15
// 183.304 us; speedup vs baseline: 4.0571x; 4.0571x over previous
//
#include <hip/hip_runtime.h>

#define F_IN 128
#define F_OUT 64
#define LSTR 136
#define EB 4096          // edges per scatter chunk
#define BSH 8            // bucket = node >> 8  (256 nodes per bucket)
#define BNODES 256
#define BCAP 4608        // slots per bucket region; mean 4092, +8 sigma
#define RITER 5          // 5*1024 = 5120 >= BCAP reg slots for bucket sort

typedef __bf16 bf16x8 __attribute__((ext_vector_type(8)));
typedef float f32x4 __attribute__((ext_vector_type(4)));

__device__ inline ushort f2bf(float f) {
    unsigned u = __float_as_uint(f);
    return (ushort)((u + 0x7fff + ((u >> 16) & 1)) >> 16);
}
__device__ inline float bf2f(ushort u) { return __uint_as_float((unsigned)u << 16); }

// ---- k1: blocks [0,nblk): scatter into FIXED-CAPACITY bucket regions.
//      Per chunk: LDS bucket count -> wave-shuffle scan (2 barriers, was 18)
//      -> ONE global atomicAdd per (chunk,bucket) reserves run space ->
//      LDS counting sort (regs staged) -> contiguous run writes.
//      blocks [nblk,...): bf16 MFMA GEMM (xwb = bf16(X@W)) rides along. ----
__global__ __launch_bounds__(512) void k_scatter_gemm(
        const float* __restrict__ X, const float* __restrict__ W,
        const int* __restrict__ ei, const float* __restrict__ ew,
        unsigned* __restrict__ bcnt, unsigned* __restrict__ sortedA,
        unsigned char* __restrict__ cl, ushort* __restrict__ xwb,
        int n, int e, int nblk, int nbuck) {
    __shared__ union SM {
        struct {
            unsigned srt[EB];     // 16 KB
            unsigned meta[EB];    // 16 KB (full 17-bit target id)
            unsigned cnt[512];
            unsigned ptr[512];
            unsigned delta[512];
            unsigned wsum[8];
        } sc;
        ushort Wt[64 * LSTR];     // 17 KB (GEMM branch)
    } sm;
    const int t = threadIdx.x;

    if ((int)blockIdx.x >= nblk) {
        // ---- GEMM: 128 rows x 64 cols, K=128, mfma_f32_16x16x32_bf16 ----
        ushort* Wt = sm.Wt;
        const int row0 = ((int)blockIdx.x - nblk) * 128;
        const float4* W4 = (const float4*)W;
        #pragma unroll
        for (int i = 0; i < 4; ++i) {
            int idx = t + i * 512;  // 2048 float4s = 128x64 W
            float4 v = W4[idx];
            int flat = idx * 4;
            int k = flat >> 6, c = flat & 63;
            Wt[(c + 0) * LSTR + k] = f2bf(v.x);
            Wt[(c + 1) * LSTR + k] = f2bf(v.y);
            Wt[(c + 2) * LSTR + k] = f2bf(v.z);
            Wt[(c + 3) * LSTR + k] = f2bf(v.w);
        }
        const int lane = t & 63, wv_ = t >> 6;       // 8 waves x 16 rows
        const int m16 = lane & 15, quad = lane >> 4;
        int arow = row0 + wv_ * 16 + m16;
        if (arow >= n) arow = n - 1;  // clamp; store is guarded
        const float* xr = X + (long)arow * F_IN;
        __syncthreads();

        f32x4 acc[4] = {{0,0,0,0},{0,0,0,0},{0,0,0,0},{0,0,0,0}};
        #pragma unroll
        for (int kk = 0; kk < 4; ++kk) {
            float4 xa = *(const float4*)(xr + kk * 32 + quad * 8);
            float4 xb = *(const float4*)(xr + kk * 32 + quad * 8 + 4);
            union { ushort us[8]; bf16x8 v; } ua;
            ua.us[0] = f2bf(xa.x); ua.us[1] = f2bf(xa.y);
            ua.us[2] = f2bf(xa.z); ua.us[3] = f2bf(xa.w);
            ua.us[4] = f2bf(xb.x); ua.us[5] = f2bf(xb.y);
            ua.us[6] = f2bf(xb.z); ua.us[7] = f2bf(xb.w);
            #pragma unroll
            for (int nt = 0; nt < 4; ++nt) {
                bf16x8 bb = *(const bf16x8*)&Wt[(nt * 16 + m16) * LSTR + kk * 32 + quad * 8];
                acc[nt] = __builtin_amdgcn_mfma_f32_16x16x32_bf16(ua.v, bb, acc[nt], 0, 0, 0);
            }
        }
        #pragma unroll
        for (int nt = 0; nt < 4; ++nt) {
            #pragma unroll
            for (int reg = 0; reg < 4; ++reg) {
                int gr = row0 + wv_ * 16 + quad * 4 + reg;  // C/D: row=quad*4+reg
                if (gr < n) xwb[(long)gr * F_OUT + nt * 16 + m16] = f2bf(acc[nt][reg]);
            }
        }
        return;
    }

    // ---- scatter branch ----
    const int blk = (int)blockIdx.x;
    sm.sc.cnt[t] = 0;
    __syncthreads();

    // pass 1: load chunk into regs (static-indexed), count buckets in LDS
    const int base = blk * EB;
    unsigned cc[EB / 512], rr[EB / 512], ww[EB / 512];
    #pragma unroll
    for (int jj = 0; jj < EB / 512; ++jj) {   // 8 iters
        int i = base + jj * 512 + t;
        unsigned c = 0xffffffffu, r = 0, w15 = 0;
        if (i < e) {
            c = (unsigned)ei[e + i];          // target
            r = (unsigned)ei[i];              // source
            unsigned u = __float_as_uint(ew[i]);
            w15 = ((u + 0x7fff + ((u >> 16) & 1)) >> 16) & 0x7fffu;
            atomicAdd(&sm.sc.cnt[c >> BSH], 1u);
        }
        cc[jj] = c; rr[jj] = r; ww[jj] = w15;
    }
    __syncthreads();

    // wave-shuffle scan of cnt[512] (2 barriers, replaces 18-barrier H-S scan)
    const unsigned cv = sm.sc.cnt[t];
    unsigned x = cv;
    #pragma unroll
    for (int d = 1; d < 64; d <<= 1) {
        unsigned y = __shfl_up(x, d, 64);
        if ((t & 63) >= d) x += y;
    }
    if ((t & 63) == 63) sm.sc.wsum[t >> 6] = x;   // wave totals
    __syncthreads();
    if (t < 8) {
        unsigned wv = sm.sc.wsum[t];
        #pragma unroll
        for (int d = 1; d < 8; d <<= 1) {
            unsigned y = __shfl_up(wv, d, 64);
            if (t >= d) wv += y;
        }
        sm.sc.wsum[t] = wv;                        // inclusive wave prefix
    }
    __syncthreads();
    const unsigned incl = x + ((t >> 6) ? sm.sc.wsum[(t >> 6) - 1] : 0);
    const unsigned excl = incl - cv;
    sm.sc.ptr[t] = excl;
    unsigned rbase = (t < nbuck && cv > 0) ? atomicAdd(&bcnt[t], cv) : 0;
    sm.sc.delta[t] = (unsigned)t * BCAP + rbase - excl;
    __syncthreads();

    // pass 2: place records into LDS, bucket-sorted
    #pragma unroll
    for (int jj = 0; jj < EB / 512; ++jj) {
        if (cc[jj] != 0xffffffffu) {
            unsigned d = atomicAdd(&sm.sc.ptr[cc[jj] >> BSH], 1u);
            sm.sc.srt[d] = (rr[jj] << 15) | ww[jj];
            sm.sc.meta[d] = cc[jj];
        }
    }
    __syncthreads();

    // pass 3: contiguous run writes (consecutive lds idx -> consecutive dest)
    const int cnum = (e - base < EB) ? (e - base) : EB;
    #pragma unroll
    for (int jj = 0; jj < EB / 512; ++jj) {
        int i = jj * 512 + t;
        if (i < cnum) {
            unsigned c = sm.sc.meta[i];
            unsigned bb = c >> BSH;
            unsigned dest = sm.sc.delta[bb] + (unsigned)i;
            if (dest < (bb + 1) * BCAP) {   // overflow guard (P ~ 1e-15)
                sortedA[dest] = sm.sc.srt[i];
                cl[dest] = (unsigned char)(c & (BNODES - 1));
            }
        }
    }
}

// ---- k2: ONE counting sort per bucket + deg (1024 threads). Records staged
//      in REGISTERS (static indices), counted + weight-summed in LDS,
//      scattered back IN PLACE node-exactly. Wave-shuffle scan (2 barriers,
//      was 16). Emits nbeg[c], ncnt[c] (node-exact CSR) and dis[c]. ----
__global__ __launch_bounds__(1024) void k_sort_deg(
        unsigned* __restrict__ sortedA, const unsigned char* __restrict__ cl,
        const unsigned* __restrict__ bcnt, unsigned* __restrict__ nbeg,
        ushort* __restrict__ ncnt, float* __restrict__ dis, int n) {
    __shared__ unsigned cnt[BNODES];
    __shared__ unsigned offs[BNODES];
    __shared__ unsigned ptr[BNODES];
    __shared__ float dl[BNODES];
    __shared__ unsigned wsum[4];
    const int b = (int)blockIdx.x, t = threadIdx.x;
    const unsigned S = (unsigned)b * BCAP;
    unsigned bc = bcnt[b];
    const int seg = (int)(bc < BCAP ? bc : BCAP);   // <= RITER*1024

    if (t < BNODES) { cnt[t] = 0; dl[t] = 0.f; }
    __syncthreads();

    unsigned rec[RITER];
    unsigned clp[(RITER + 3) / 4];   // 4 local-ids packed per u32, static shifts
    #pragma unroll
    for (int jj = 0; jj < RITER; ++jj) {
        int j = jj * 1024 + t;
        unsigned r = 0, c = 0;
        if (j < seg) {
            r = sortedA[S + j];
            c = cl[S + j];
            atomicAdd(&cnt[c], 1u);
            atomicAdd(&dl[c], __uint_as_float((r & 0x7fffu) << 16));
        }
        rec[jj] = r;
        if ((jj & 3) == 0) clp[jj >> 2] = c;
        else               clp[jj >> 2] |= c << ((jj & 3) * 8);
    }
    __syncthreads();
    // wave-shuffle scan of cnt[256] using threads 0..255 (4 waves)
    unsigned x = 0, mycnt = 0;
    if (t < BNODES) {
        mycnt = cnt[t];
        x = mycnt;
        #pragma unroll
        for (int d = 1; d < 64; d <<= 1) {
            unsigned y = __shfl_up(x, d, 64);
            if ((t & 63) >= d) x += y;
        }
        if ((t & 63) == 63) wsum[t >> 6] = x;
    }
    __syncthreads();
    if (t < 4) {
        unsigned wv = wsum[t];
        #pragma unroll
        for (int d = 1; d < 4; d <<= 1) {
            unsigned y = __shfl_up(wv, d, 64);
            if (t >= d) wv += y;
        }
        wsum[t] = wv;
    }
    __syncthreads();
    if (t < BNODES) {
        unsigned incl = x + ((t >> 6) ? wsum[(t >> 6) - 1] : 0);
        offs[t] = incl;
        ptr[t] = incl - mycnt;   // exclusive start
    }
    __syncthreads();
    #pragma unroll
    for (int jj = 0; jj < RITER; ++jj) {
        int j = jj * 1024 + t;
        if (j < seg) {
            unsigned c = (clp[jj >> 2] >> ((jj & 3) * 8)) & 0xffu;
            unsigned d = atomicAdd(&ptr[c], 1u);
            sortedA[S + d] = rec[jj];   // safe: all reads staged in regs
        }
    }
    if (t < BNODES) {
        int c = b * BNODES + t;
        if (c < n) {
            nbeg[c] = S + (offs[t] - cnt[t]);
            ncnt[c] = (ushort)cnt[t];
            dis[c] = rsqrtf(dl[t] + 1.0f);
        }
    }
}

// ---- k3: gather, LDS-free. Wave per node; QUARTER-wave (16 lanes) per edge
//      stream; lane fl handles features 4fl..4fl+3 (ushort4 = 8B of 128B row).
//      MASKED 4-in-flight: every iteration issues 4 independent loads.
//      out = dc*(dc*xw[c] + sum w*dis[r]*xw[r]) + b, ReLU ----
__global__ __launch_bounds__(256, 8) void k_gather(
        const unsigned* __restrict__ sortedA, const unsigned* __restrict__ nbeg,
        const ushort* __restrict__ ncnt, const float* __restrict__ dis,
        const ushort* __restrict__ xwb, const float* __restrict__ bias,
        float* __restrict__ out, int n) {
    int node = (int)blockIdx.x * 4 + (threadIdx.x >> 6);
    if (node >= n) return;
    int lane = threadIdx.x & 63, q = lane >> 4, fl = lane & 15;
    int beg = (int)nbeg[node];
    int end = beg + (int)ncnt[node];
    float dc = dis[node];
    float a0 = 0.f, a1 = 0.f, a2 = 0.f, a3 = 0.f;
    if (q == 0) {  // self-loop term: dc*xw here, final *dc => dc^2*xw
        ushort4 xv = *(const ushort4*)(xwb + (long)node * 64 + fl * 4);
        a0 = dc * bf2f(xv.x); a1 = dc * bf2f(xv.y);
        a2 = dc * bf2f(xv.z); a3 = dc * bf2f(xv.w);
    }
    for (int j = beg + q; j < end; j += 16) {
        bool m1 = j + 4 < end, m2 = j + 8 < end, m3 = j + 12 < end;
        int j1 = m1 ? j + 4 : j, j2 = m2 ? j + 8 : j, j3 = m3 ? j + 12 : j;
        unsigned v0 = sortedA[j],  v1 = sortedA[j1];
        unsigned v2 = sortedA[j2], v3 = sortedA[j3];
        int r0 = (int)(v0 >> 15), r1 = (int)(v1 >> 15);
        int r2 = (int)(v2 >> 15), r3 = (int)(v3 >> 15);
        float d0 = dis[r0], d1 = dis[r1], d2 = dis[r2], d3 = dis[r3];
        ushort4 x0 = *(const ushort4*)(xwb + (long)r0 * 64 + fl * 4);
        ushort4 x1 = *(const ushort4*)(xwb + (long)r1 * 64 + fl * 4);
        ushort4 x2 = *(const ushort4*)(xwb + (long)r2 * 64 + fl * 4);
        ushort4 x3 = *(const ushort4*)(xwb + (long)r3 * 64 + fl * 4);
        float w0 = __uint_as_float((v0 & 0x7fffu) << 16) * d0;
        float w1 = m1 ? __uint_as_float((v1 & 0x7fffu) << 16) * d1 : 0.f;
        float w2 = m2 ? __uint_as_float((v2 & 0x7fffu) << 16) * d2 : 0.f;
        float w3 = m3 ? __uint_as_float((v3 & 0x7fffu) << 16) * d3 : 0.f;
        a0 += w0 * bf2f(x0.x) + w1 * bf2f(x1.x) + w2 * bf2f(x2.x) + w3 * bf2f(x3.x);
        a1 += w0 * bf2f(x0.y) + w1 * bf2f(x1.y) + w2 * bf2f(x2.y) + w3 * bf2f(x3.y);
        a2 += w0 * bf2f(x0.z) + w1 * bf2f(x1.z) + w2 * bf2f(x2.z) + w3 * bf2f(x3.z);
        a3 += w0 * bf2f(x0.w) + w1 * bf2f(x1.w) + w2 * bf2f(x2.w) + w3 * bf2f(x3.w);
    }
    a0 += __shfl_xor(a0, 16); a0 += __shfl_xor(a0, 32);
    a1 += __shfl_xor(a1, 16); a1 += __shfl_xor(a1, 32);
    a2 += __shfl_xor(a2, 16); a2 += __shfl_xor(a2, 32);
    a3 += __shfl_xor(a3, 16); a3 += __shfl_xor(a3, 32);
    if (q == 0) {
        float4 bb = ((const float4*)bias)[fl];
        float f0 = dc * a0 + bb.x, f1 = dc * a1 + bb.y;
        float f2 = dc * a2 + bb.z, f3 = dc * a3 + bb.w;
        ((float4*)out)[(long)node * 16 + fl] =
            make_float4(f0 > 0.f ? f0 : 0.f, f1 > 0.f ? f1 : 0.f,
                        f2 > 0.f ? f2 : 0.f, f3 > 0.f ? f3 : 0.f);
    }
}

extern "C" void kernel_launch(void* const* d_in, const int* in_sizes, int n_in,
                              void* d_out, int out_size, void* d_ws, size_t ws_size,
                              hipStream_t stream) {
    const float* X  = (const float*)d_in[0];
    const int*   ei = (const int*)d_in[1];
    const float* ew = (const float*)d_in[2];
    const float* W  = (const float*)d_in[3];
    const float* b  = (const float*)d_in[4];
    float* out = (float*)d_out;

    const int n = in_sizes[0] / F_IN;   // 100000
    const int e = in_sizes[2];          // 1600000

    const int NBLK  = (e + EB - 1) / EB;            // 391  (<=512 for e<=2.09M)
    const int NBUCK = (n + BNODES - 1) / BNODES;    // 391  (<=512 for n<=131072)
    const int nb_gemm = (n + 127) / 128;            // 782 (128 rows per block)

    long p = 0;
    auto alloc = [&](long bytes) { long off = p; p += (bytes + 255) & ~255L; return off; };
    char* ws = (char*)d_ws;
    long o_bcnt   = alloc((long)NBUCK * 4);         // 1.6 KB (zeroed by memset)
    long o_sorted = alloc((long)NBUCK * BCAP * 4);  // 7.2 MB fixed-cap regions
    long o_cl     = alloc((long)NBUCK * BCAP);      // 1.8 MB
    long o_dis    = alloc((long)n * 4);             // 400 KB
    long o_nbeg   = alloc((long)n * 4);             // 400 KB
    long o_ncnt   = alloc((long)n * 2);             // 200 KB
    long o_xwb    = alloc((long)n * F_OUT * 2);     // 12.8 MB  -> total ~22.8 MB
    unsigned*      bcnt    = (unsigned*)(ws + o_bcnt);
    unsigned*      sortedA = (unsigned*)(ws + o_sorted);
    unsigned char* cl      = (unsigned char*)(ws + o_cl);
    float*         dis     = (float*)(ws + o_dis);
    unsigned*      nbeg    = (unsigned*)(ws + o_nbeg);
    ushort*        ncnt    = (ushort*)(ws + o_ncnt);
    ushort*        xwb     = (ushort*)(ws + o_xwb);

    hipMemsetAsync(ws + o_bcnt, 0, (size_t)NBUCK * 4, stream);  // bcnt only
    k_scatter_gemm<<<NBLK + nb_gemm, 512, 0, stream>>>(X, W, ei, ew, bcnt,
                                                       sortedA, cl, xwb,
                                                       n, e, NBLK, NBUCK);
    k_sort_deg<<<NBUCK, 1024, 0, stream>>>(sortedA, cl, bcnt, nbeg, ncnt, dis, n);
    k_gather<<<(n + 3) / 4, 256, 0, stream>>>(sortedA, nbeg, ncnt, dis, xwb,
                                              b, out, n);
}